// Round 13
// baseline (140.589 us; speedup 1.0000x reference)
//
#include <hip/hip_runtime.h>
#include <hip/hip_bf16.h>
#include <float.h>

// Problem constants: B=16, M=4096.
#define NB 16
#define MPTS 4096
#define NPRED (NB * MPTS)       // 65536 pred points
#define GTQ 8                   // gt eighths (one per block)
#define GTN 512                 // gt points per block
#define NT 16                   // MFMA tiles of 32 gt each per block
#define BLK 256                 // 4 waves
#define FRAGS 4                 // B-fragments (preds) per wave: 4*32 = 128
#define PREDS_PER_BLK 512       // 4 waves * 128
#define PGRP 8                  // pred groups per batch (4096/512)
#define NGRP (NB * PGRP)        // 128 (b,pg) groups

typedef _Float16 half8 __attribute__((ext_vector_type(8)));
typedef float f32x16 __attribute__((ext_vector_type(16)));

// Split x into f16 hi + f16 lo (x ~= hi + lo).
__device__ inline void split16(float x, _Float16& hi, _Float16& lo) {
    hi = (_Float16)x;
    lo = (_Float16)(x - (float)hi);
}

__device__ inline float aload(const float* p) {
    return __hip_atomic_load(p, __ATOMIC_RELAXED, __HIP_MEMORY_SCOPE_AGENT);
}

// Single kernel + async-memset of tickets. One block = (b, pg, gtq).
// S[gt][pred] = gn - 2 p.g via mfma_f32_32x32x16_f16, hi/lo split K-slots
// (R7-proven). pmin[grp][gtq][512]; gcnt zeroed each call by memset so the
// EXACT 8th arriver (old==7) finishes its group (acq-rel ticket + relaxed
// agent atomic loads = R5-validated visibility pattern); last group-finisher
// (old2==127) sums 128 partials in fixed order -> out[0] (bit-deterministic).
__global__ __launch_bounds__(BLK, 4) void adds_mfma(
    const float* __restrict__ pred_R, const float* __restrict__ pred_t,
    const float* __restrict__ gt_R,   const float* __restrict__ gt_t,
    const float* __restrict__ mp,     float* __restrict__ pmin,
    unsigned* __restrict__ gcnt,      unsigned* __restrict__ gcnt2,
    float* __restrict__ partial,      float* __restrict__ out)
{
    __shared__ half8 aT[NT * 64];        // 16 KB, [tile][vlane]
    __shared__ float wsum[4];
    __shared__ int flag;

    const int bid = blockIdx.x;
    const int gtq = bid & (GTQ - 1);
    const int pg  = (bid >> 3) & (PGRP - 1);
    const int b   = bid >> 6;
    const int grp = bid >> 3;            // (b,pg), 0..127
    const int tid = threadIdx.x;
    const int ln  = tid & 63;
    const int wv  = tid >> 6;

    // ---- stage A tiles: 512 points, one transform per point, 2 entries ----
    {
        float gR[9];
#pragma unroll
        for (int i = 0; i < 9; ++i) gR[i] = gt_R[b * 9 + i];
        const float gtx = gt_t[b * 3 + 0];
        const float gty = gt_t[b * 3 + 1];
        const float gtz = gt_t[b * 3 + 2];

#pragma unroll
        for (int j = 0; j < GTN / BLK; ++j) {         // 2 points per thread
            const int nl = j * BLK + tid;             // 0..511
            const int n  = gtq * GTN + nl;
            const float mx = mp[n * 3 + 0];
            const float my = mp[n * 3 + 1];
            const float mz = mp[n * 3 + 2];
            const float gx = fmaf(gR[0], mx, fmaf(gR[1], my, fmaf(gR[2], mz, gtx)));
            const float gy = fmaf(gR[3], mx, fmaf(gR[4], my, fmaf(gR[5], mz, gty)));
            const float gz = fmaf(gR[6], mx, fmaf(gR[7], my, fmaf(gR[8], mz, gtz)));
            const float gn = fmaf(gx, gx, fmaf(gy, gy, gz * gz));
            const float ux = -2.0f * gx, uy = -2.0f * gy, uz = -2.0f * gz;
            _Float16 hux, lux, huy, luy, huz, luz, gnh, gnl;
            split16(ux, hux, lux);
            split16(uy, huy, luy);
            split16(uz, huz, luz);
            split16(gn, gnh, gnl);
            half8 k0, k1;
            k0[0] = hux; k0[1] = huy; k0[2] = huz;
            k0[3] = hux; k0[4] = huy; k0[5] = huz;
            k0[6] = lux; k0[7] = luy;
            k1[0] = luz; k1[1] = gnh; k1[2] = gnl;
            k1[3] = (_Float16)0.0f; k1[4] = (_Float16)0.0f; k1[5] = (_Float16)0.0f;
            k1[6] = (_Float16)0.0f; k1[7] = (_Float16)0.0f;
            const int t = nl >> 5, r = nl & 31;
            aT[t * 64 + r]      = k0;
            aT[t * 64 + 32 + r] = k1;
        }
    }

    // ---- B-fragments (pred side), constant across tiles ----
    float pR[9];
#pragma unroll
    for (int i = 0; i < 9; ++i) pR[i] = pred_R[b * 9 + i];
    const float ptx = pred_t[b * 3 + 0];
    const float pty = pred_t[b * 3 + 1];
    const float ptz = pred_t[b * 3 + 2];

    half8 bf[FRAGS];
    float pn[FRAGS];
    const int kh = ln >> 5;
#pragma unroll
    for (int f = 0; f < FRAGS; ++f) {
        const int predl = pg * PREDS_PER_BLK + wv * 128 + f * 32 + (ln & 31);
        const float mx = mp[predl * 3 + 0];
        const float my = mp[predl * 3 + 1];
        const float mz = mp[predl * 3 + 2];
        const float px = fmaf(pR[0], mx, fmaf(pR[1], my, fmaf(pR[2], mz, ptx)));
        const float py = fmaf(pR[3], mx, fmaf(pR[4], my, fmaf(pR[5], mz, pty)));
        const float pz = fmaf(pR[6], mx, fmaf(pR[7], my, fmaf(pR[8], mz, ptz)));
        pn[f] = fmaf(px, px, fmaf(py, py, pz * pz));
        _Float16 hpx, lpx, hpy, lpy, hpz, lpz;
        split16(px, hpx, lpx);
        split16(py, hpy, lpy);
        split16(pz, hpz, lpz);
        half8 v;
        if (kh == 0) {
            v[0] = hpx; v[1] = hpy; v[2] = hpz;
            v[3] = lpx; v[4] = lpy; v[5] = lpz;
            v[6] = hpx; v[7] = hpy;
        } else {
            v[0] = hpz; v[1] = (_Float16)1.0f; v[2] = (_Float16)1.0f;
            v[3] = (_Float16)0.0f; v[4] = (_Float16)0.0f;
            v[5] = (_Float16)0.0f; v[6] = (_Float16)0.0f;
            v[7] = (_Float16)0.0f;
        }
        bf[f] = v;
    }

    __syncthreads();

    // ---- MFMA loop over 16 gt tiles (2+2 MFMA groups) ----
    f32x16 zc;
#pragma unroll
    for (int i = 0; i < 16; ++i) zc[i] = 0.0f;

    float best[FRAGS][8];
#pragma unroll
    for (int f = 0; f < FRAGS; ++f)
#pragma unroll
        for (int j = 0; j < 8; ++j) best[f][j] = FLT_MAX;

    half8 a_cur = aT[ln];
    for (int t = 0; t < NT; ++t) {
        const half8 a_nxt = (t + 1 < NT) ? aT[(t + 1) * 64 + ln] : a_cur;
        {
            const f32x16 d0 = __builtin_amdgcn_mfma_f32_32x32x16_f16(a_cur, bf[0], zc, 0, 0, 0);
            const f32x16 d1 = __builtin_amdgcn_mfma_f32_32x32x16_f16(a_cur, bf[1], zc, 0, 0, 0);
#pragma unroll
            for (int j = 0; j < 8; ++j) {
                best[0][j] = fminf(best[0][j], fminf(d0[2 * j], d0[2 * j + 1]));
                best[1][j] = fminf(best[1][j], fminf(d1[2 * j], d1[2 * j + 1]));
            }
        }
        {
            const f32x16 d2 = __builtin_amdgcn_mfma_f32_32x32x16_f16(a_cur, bf[2], zc, 0, 0, 0);
            const f32x16 d3 = __builtin_amdgcn_mfma_f32_32x32x16_f16(a_cur, bf[3], zc, 0, 0, 0);
#pragma unroll
            for (int j = 0; j < 8; ++j) {
                best[2][j] = fminf(best[2][j], fminf(d2[2 * j], d2[2 * j + 1]));
                best[3][j] = fminf(best[3][j], fminf(d3[2 * j], d3[2 * j + 1]));
            }
        }
        a_cur = a_nxt;
    }

    // ---- epilogue: fold, merge lane halves, add pn, store group slab ----
#pragma unroll
    for (int f = 0; f < FRAGS; ++f) {
        float r = fminf(fminf(fminf(best[f][0], best[f][1]), fminf(best[f][2], best[f][3])),
                        fminf(fminf(best[f][4], best[f][5]), fminf(best[f][6], best[f][7])));
        r = fminf(r, __shfl_xor(r, 32, 64));
        const float d2v = fmaxf(pn[f] + r, 0.0f);
        if (ln < 32) {
            const int li = wv * 128 + f * 32 + ln;             // 0..511
            pmin[(grp * GTQ + gtq) * PREDS_PER_BLK + li] = d2v;
        }
    }

    // ---- group ticket: EXACT 8th arriver (gcnt zeroed by memset) ----
    __threadfence();
    if (tid == 0) {
        const unsigned old = __hip_atomic_fetch_add(
            &gcnt[grp], 1u, __ATOMIC_ACQ_REL, __HIP_MEMORY_SCOPE_AGENT);
        flag = (old == 7u) ? 1 : 0;
    }
    __syncthreads();
    if (!flag) return;

    // group finish: min over 8 gtq slabs (relaxed agent loads), sqrt, sum
    float s = 0.0f;
#pragma unroll
    for (int half = 0; half < 2; ++half) {
        const int i = half * BLK + tid;                        // 0..511
        const float* base = pmin + (size_t)grp * GTQ * PREDS_PER_BLK + i;
        float m0 = fminf(aload(base + 0 * PREDS_PER_BLK), aload(base + 1 * PREDS_PER_BLK));
        float m1 = fminf(aload(base + 2 * PREDS_PER_BLK), aload(base + 3 * PREDS_PER_BLK));
        float m2 = fminf(aload(base + 4 * PREDS_PER_BLK), aload(base + 5 * PREDS_PER_BLK));
        float m3 = fminf(aload(base + 6 * PREDS_PER_BLK), aload(base + 7 * PREDS_PER_BLK));
        s += sqrtf(fminf(fminf(m0, m1), fminf(m2, m3)));
    }
#pragma unroll
    for (int off = 32; off > 0; off >>= 1) s += __shfl_down(s, off, 64);
    if (ln == 0) wsum[wv] = s;
    __syncthreads();

    if (tid == 0) {
        partial[grp] = (wsum[0] + wsum[1]) + (wsum[2] + wsum[3]);
        __threadfence();
        const unsigned old2 = __hip_atomic_fetch_add(
            gcnt2, 1u, __ATOMIC_ACQ_REL, __HIP_MEMORY_SCOPE_AGENT);
        flag = (old2 == 127u) ? 1 : 0;
    }
    __syncthreads();
    if (!flag) return;

    // final: fixed-order reduction of 128 group partials -> out[0]
    if (tid < 128) {
        float v = aload(&partial[tid]);
#pragma unroll
        for (int off = 32; off > 0; off >>= 1) v += __shfl_down(v, off, 64);
        if ((tid & 63) == 0) wsum[tid >> 6] = v;
    }
    __syncthreads();
    if (tid == 0) out[0] = (wsum[0] + wsum[1]) * (1.0f / (float)NPRED);
}

extern "C" void kernel_launch(void* const* d_in, const int* in_sizes, int n_in,
                              void* d_out, int out_size, void* d_ws, size_t ws_size,
                              hipStream_t stream) {
    const float* pred_R = (const float*)d_in[0];
    const float* pred_t = (const float*)d_in[1];
    const float* gt_R   = (const float*)d_in[2];
    const float* gt_t   = (const float*)d_in[3];
    const float* mp     = (const float*)d_in[4];
    float* out = (float*)d_out;

    char* ws = (char*)d_ws;
    float*    pmin    = (float*)ws;                            // 128*8*512*4 = 2 MB
    unsigned* gcnt    = (unsigned*)(ws + (size_t)NGRP * GTQ * PREDS_PER_BLK * 4);
    unsigned* gcnt2   = gcnt + NGRP;
    float*    partial = (float*)(gcnt2 + 64);                  // 128 floats

    // zero the tickets every call (graph-capturable async memset)
    hipMemsetAsync(gcnt, 0, (NGRP + 64) * sizeof(unsigned), stream);

    // grid: b(16) x pred-group(8) x gtq(8) = 1024 blocks (4 blocks/CU)
    adds_mfma<<<dim3(NB * PGRP * GTQ), dim3(BLK), 0, stream>>>(
        pred_R, pred_t, gt_R, gt_t, mp, pmin, gcnt, gcnt2, partial, out);
}